// Round 1
// baseline (181.531 us; speedup 1.0000x reference)
//
#include <hip/hip_runtime.h>

typedef _Float16 half_t;
typedef _Float16 hx8 __attribute__((ext_vector_type(8)));
typedef _Float16 hx4 __attribute__((ext_vector_type(4)));
typedef float fx4 __attribute__((ext_vector_type(4)));

#define LOG2E 1.44269504088896f
#define TAU 0.1f

// ---------------- Kernel 1: T = relu(Z@W1+b1)@W2+b2  -> fp16 ----------------
// 64 rows/block, 256 threads. W streamed from global (L2-resident, 64KB each).
// H exchanged through LDS. Known-suboptimal (fp32 VALU); ~0.5 GFLOP total.
__global__ __launch_bounds__(256) void mlp_kernel(
    const float* __restrict__ Z, const float* __restrict__ W1,
    const float* __restrict__ b1, const float* __restrict__ W2,
    const float* __restrict__ b2, half_t* __restrict__ T)
{
  __shared__ float Hs[64*132];          // +4 pad breaks 128-stride bank aliasing
  const int tid = threadIdx.x;
  const int x  = tid & 15;              // row base (rows x, x+16, x+32, x+48)
  const int cg = tid >> 4;              // col group: cols cg*8 .. cg*8+7
  const int rb = blockIdx.x * 64;

  float acc[4][8];
#pragma unroll
  for (int ri=0;ri<4;++ri)
#pragma unroll
    for (int cc=0;cc<8;++cc) acc[ri][cc] = b1[cg*8+cc];

  for (int k=0;k<128;k+=4) {
    fx4 z[4];
#pragma unroll
    for (int ri=0;ri<4;++ri) z[ri] = *(const fx4*)(Z + (size_t)(rb + x + 16*ri)*128 + k);
#pragma unroll
    for (int kk=0;kk<4;++kk) {
      fx4 wA = *(const fx4*)(W1 + (k+kk)*128 + cg*8);
      fx4 wB = *(const fx4*)(W1 + (k+kk)*128 + cg*8 + 4);
#pragma unroll
      for (int ri=0;ri<4;++ri) {
        float zz = z[ri][kk];
#pragma unroll
        for (int cc=0;cc<4;++cc) { acc[ri][cc] += zz*wA[cc]; acc[ri][4+cc] += zz*wB[cc]; }
      }
    }
  }
#pragma unroll
  for (int ri=0;ri<4;++ri)
#pragma unroll
    for (int cc=0;cc<8;++cc) {
      float h = acc[ri][cc];
      Hs[(x+16*ri)*132 + cg*8 + cc] = h > 0.f ? h : 0.f;
    }
  __syncthreads();

#pragma unroll
  for (int ri=0;ri<4;++ri)
#pragma unroll
    for (int cc=0;cc<8;++cc) acc[ri][cc] = b2[cg*8+cc];

  for (int k=0;k<128;k+=4) {
    fx4 z[4];
#pragma unroll
    for (int ri=0;ri<4;++ri) z[ri] = *(const fx4*)(&Hs[(x+16*ri)*132 + k]);
#pragma unroll
    for (int kk=0;kk<4;++kk) {
      fx4 wA = *(const fx4*)(W2 + (k+kk)*128 + cg*8);
      fx4 wB = *(const fx4*)(W2 + (k+kk)*128 + cg*8 + 4);
#pragma unroll
      for (int ri=0;ri<4;++ri) {
        float zz = z[ri][kk];
#pragma unroll
        for (int cc=0;cc<4;++cc) { acc[ri][cc] += zz*wA[cc]; acc[ri][4+cc] += zz*wB[cc]; }
      }
    }
  }
#pragma unroll
  for (int ri=0;ri<4;++ri) {
    hx8 hv;
#pragma unroll
    for (int cc=0;cc<8;++cc) hv[cc] = (half_t)acc[ri][cc];
    *(hx8*)(T + (size_t)(rb + x + 16*ri)*128 + cg*8) = hv;
  }
}

// ---------------- Kernel 2: Zt[d][n] = (fp16) Z[n][d] ----------------
// 64(N) x 32(D) tiles; grid = 128 * 4 = 512 blocks.
__global__ __launch_bounds__(256) void ztrans_kernel(
    const float* __restrict__ Z, half_t* __restrict__ Zth)
{
  __shared__ float tile[64*36];         // stride 36: fx4-aligned, conflict-light
  const int tid = threadIdx.x;
  const int nb = blockIdx.x >> 2;
  const int db = blockIdx.x & 3;
#pragma unroll
  for (int i=0;i<2;++i) {
    int fid = i*256 + tid;
    int r = fid >> 3, c4 = (fid & 7) * 4;
    *(fx4*)(&tile[r*36 + c4]) = *(const fx4*)(Z + (size_t)(nb*64 + r)*128 + db*32 + c4);
  }
  __syncthreads();
  const int cr = tid >> 3, j = tid & 7, n0 = j*8;
  hx8 hv;
#pragma unroll
  for (int idx=0;idx<8;++idx) hv[idx] = (half_t)tile[(n0+idx)*36 + cr];
  *(hx8*)(Zth + (size_t)(db*32 + cr)*8192 + nb*64 + n0) = hv;
}

// ---------------- Kernel 3: flash attention partials ----------------
// grid 512 = 64 query-blocks(128 rows) x 8 key-splits(1024 keys = 16 tiles of 64)
// 4 waves x 32 rows/wave. mfma_f32_16x16x32_f16.
// LDS tiles stored FRAGMENT-LINEAR: frag f occupies [f*512 .. f*512+511] halfs,
// lane L's 8 values at f*512 + L*8 -> ds_read_b128 conflict-free.
__global__ __launch_bounds__(256,2) void flash_kernel(
    const half_t* __restrict__ T, const half_t* __restrict__ Zt,
    half_t* __restrict__ Pacc, float* __restrict__ Pm, float* __restrict__ Pl)
{
  __shared__ half_t Tks[16*512];        // 16 frags (nt,ks): key-tile for scores
  __shared__ half_t Zts[16*512];        // 16 frags (nz,ks2): Z^T tile for PV
  __shared__ half_t Ps[4][32*72];       // per-wave P round-trip, stride 72
  const int tid = threadIdx.x;
  const int w = tid >> 6, lane = tid & 63;
  const int q = lane >> 4, c = lane & 15;
  const int bx = blockIdx.x;
  const int qb = bx >> 3, kh = bx & 7;
  const int wrow = qb*128 + w*32;

  // Tq A-fragments pinned in registers for all 16 key tiles.
  // A layout: lane holds A[m=lane&15][k=(lane>>4)*8+j]
  hx8 aq[2][4];
#pragma unroll
  for (int mt=0;mt<2;++mt)
#pragma unroll
    for (int ks=0;ks<4;++ks)
      aq[mt][ks] = *(const hx8*)(T + (size_t)(wrow + mt*16 + c)*128 + ks*32 + q*8);

  fx4 oacc[2][8];
#pragma unroll
  for (int mt=0;mt<2;++mt)
#pragma unroll
    for (int nz=0;nz<8;++nz) oacc[mt][nz] = (fx4){0.f,0.f,0.f,0.f};
  fx4 mst[2], lst[2];
#pragma unroll
  for (int mt=0;mt<2;++mt) {
    mst[mt] = (fx4){-1e30f,-1e30f,-1e30f,-1e30f};
    lst[mt] = (fx4){0.f,0.f,0.f,0.f};
  }

  for (int t=0;t<16;++t) {
    const int kt0 = kh*1024 + t*64;
    __syncthreads();                    // prev iteration's LDS reads done
    // stage this tile's 32 fragments; wave w does frag ids w*8..w*8+7
#pragma unroll
    for (int i=0;i<8;++i) {
      int f = w*8 + i;
      if (f < 16) {
        int nt = f >> 2, ks = f & 3;    // B[n=key][k=dim] = T[key][dim]
        hx8 v = *(const hx8*)(T + (size_t)(kt0 + nt*16 + c)*128 + ks*32 + q*8);
        *(hx8*)(&Tks[f*512 + lane*8]) = v;
      } else {
        int f2 = f - 16, nz = f2 >> 1, ks2 = f2 & 1; // B[n=zcol][k=key] = Zt[zcol][key]
        hx8 v = *(const hx8*)(Zt + (size_t)(nz*16 + c)*8192 + kt0 + ks2*32 + q*8);
        *(hx8*)(&Zts[f2*512 + lane*8]) = v;
      }
    }
    __syncthreads();

    // ---- scores: S[32 x 64] per wave, fp32 acc ----
    fx4 sacc[2][4];
#pragma unroll
    for (int mt=0;mt<2;++mt)
#pragma unroll
      for (int nt=0;nt<4;++nt) sacc[mt][nt] = (fx4){0.f,0.f,0.f,0.f};
#pragma unroll
    for (int ks=0;ks<4;++ks)
#pragma unroll
      for (int nt=0;nt<4;++nt) {
        hx8 b = *(const hx8*)(&Tks[(nt*4+ks)*512 + lane*8]);
        sacc[0][nt] = __builtin_amdgcn_mfma_f32_16x16x32_f16(aq[0][ks], b, sacc[0][nt], 0,0,0);
        sacc[1][nt] = __builtin_amdgcn_mfma_f32_16x16x32_f16(aq[1][ks], b, sacc[1][nt], 0,0,0);
      }

    // ---- online softmax (C/D layout: row=(lane>>4)*4+reg, col=lane&15) ----
#pragma unroll
    for (int mt=0;mt<2;++mt) {
      fx4 mx;
#pragma unroll
      for (int i=0;i<4;++i)
        mx[i] = fmaxf(fmaxf(sacc[mt][0][i],sacc[mt][1][i]),fmaxf(sacc[mt][2][i],sacc[mt][3][i]));
#pragma unroll
      for (int i=0;i<4;++i) {           // reduce over the 16 col-lanes
        float v = mx[i];
        v = fmaxf(v, __shfl_xor(v,1,64));
        v = fmaxf(v, __shfl_xor(v,2,64));
        v = fmaxf(v, __shfl_xor(v,4,64));
        v = fmaxf(v, __shfl_xor(v,8,64));
        mx[i] = v;
      }
      fx4 mnew, alpha;
#pragma unroll
      for (int i=0;i<4;++i) {
        mnew[i]  = fmaxf(mst[mt][i], mx[i]);
        alpha[i] = __builtin_amdgcn_exp2f((mst[mt][i]-mnew[i])*LOG2E);
        mst[mt][i] = mnew[i];
      }
      fx4 rs = (fx4){0.f,0.f,0.f,0.f};
#pragma unroll
      for (int nt=0;nt<4;++nt)
#pragma unroll
        for (int i=0;i<4;++i) {
          float p = __builtin_amdgcn_exp2f((sacc[mt][nt][i]-mnew[i])*LOG2E);
          sacc[mt][nt][i] = p;
          rs[i] += p;
        }
#pragma unroll
      for (int i=0;i<4;++i) {
        float v = rs[i];
        v += __shfl_xor(v,1,64); v += __shfl_xor(v,2,64);
        v += __shfl_xor(v,4,64); v += __shfl_xor(v,8,64);
        rs[i] = v;
      }
#pragma unroll
      for (int i=0;i<4;++i) lst[mt][i] = lst[mt][i]*alpha[i] + rs[i];
#pragma unroll
      for (int nz=0;nz<8;++nz)
#pragma unroll
        for (int i=0;i<4;++i) oacc[mt][nz][i] *= alpha[i];
      // write P (C-layout -> row-major [32][72]); read back as A-frags below.
#pragma unroll
      for (int nt=0;nt<4;++nt)
#pragma unroll
        for (int i=0;i<4;++i)
          Ps[w][(mt*16 + q*4 + i)*72 + nt*16 + c] = (half_t)sacc[mt][nt][i];
    }

    // ---- PV: O += P @ Ztile (same-wave LDS dep; compiler inserts lgkmcnt) ----
#pragma unroll
    for (int ks2=0;ks2<2;++ks2) {
      hx8 ap0 = *(const hx8*)(&Ps[w][(c     )*72 + ks2*32 + q*8]);
      hx8 ap1 = *(const hx8*)(&Ps[w][(16 + c)*72 + ks2*32 + q*8]);
#pragma unroll
      for (int nz=0;nz<8;++nz) {
        hx8 b = *(const hx8*)(&Zts[(nz*2+ks2)*512 + lane*8]);
        oacc[0][nz] = __builtin_amdgcn_mfma_f32_16x16x32_f16(ap0, b, oacc[0][nz], 0,0,0);
        oacc[1][nz] = __builtin_amdgcn_mfma_f32_16x16x32_f16(ap1, b, oacc[1][nz], 0,0,0);
      }
    }
  }

  // epilogue: store normalized fp16 partials + (m,l)
#pragma unroll
  for (int mt=0;mt<2;++mt) {
    fx4 inv;
#pragma unroll
    for (int i=0;i<4;++i) inv[i] = 1.0f / lst[mt][i];
#pragma unroll
    for (int nz=0;nz<8;++nz)
#pragma unroll
      for (int i=0;i<4;++i)
        Pacc[(size_t)(bx*128 + w*32 + mt*16 + q*4 + i)*128 + nz*16 + c] =
            (half_t)(oacc[mt][nz][i]*inv[i]);
    if (c == 0) {
#pragma unroll
      for (int i=0;i<4;++i) {
        int rr = bx*128 + w*32 + mt*16 + q*4 + i;
        Pm[rr] = mst[mt][i];
        Pl[rr] = lst[mt][i];
      }
    }
  }
}

// ---------------- Kernel 4: merge 8 key-split partials ----------------
__global__ __launch_bounds__(256) void merge_kernel(
    const float* __restrict__ Z, const half_t* __restrict__ Pacc,
    const float* __restrict__ Pm, const float* __restrict__ Pl,
    float* __restrict__ out)
{
  const int th = blockIdx.x*256 + threadIdx.x;
  const int r = th >> 5, cg = th & 31;
  const int qb = r >> 7, rr = r & 127;
  float mk[8], lk[8];
  float M = -1e30f;
#pragma unroll
  for (int k=0;k<8;++k) {
    int p = qb*8 + k;
    mk[k] = Pm[p*128 + rr];
    lk[k] = Pl[p*128 + rr];
    M = fmaxf(M, mk[k]);
  }
  float L = 0.f, wk[8];
#pragma unroll
  for (int k=0;k<8;++k) { wk[k] = lk[k]*__builtin_amdgcn_exp2f((mk[k]-M)*LOG2E); L += wk[k]; }
  float o0=0.f,o1=0.f,o2=0.f,o3=0.f;
#pragma unroll
  for (int k=0;k<8;++k) {
    int p = qb*8 + k;
    hx4 v = *(const hx4*)(Pacc + ((size_t)p*128 + rr)*128 + cg*4);
    o0 += wk[k]*(float)v[0]; o1 += wk[k]*(float)v[1];
    o2 += wk[k]*(float)v[2]; o3 += wk[k]*(float)v[3];
  }
  float invL = 1.0f / L;
  fx4 zv = *(const fx4*)(Z + (size_t)r*128 + cg*4);
  fx4 res;
  res[0] = (1.f-TAU)*zv[0] + TAU*o0*invL;
  res[1] = (1.f-TAU)*zv[1] + TAU*o1*invL;
  res[2] = (1.f-TAU)*zv[2] + TAU*o2*invL;
  res[3] = (1.f-TAU)*zv[3] + TAU*o3*invL;
  *(fx4*)(out + (size_t)r*128 + cg*4) = res;
}

extern "C" void kernel_launch(void* const* d_in, const int* in_sizes, int n_in,
                              void* d_out, int out_size, void* d_ws, size_t ws_size,
                              hipStream_t stream) {
  const float* Z  = (const float*)d_in[0];
  const float* W1 = (const float*)d_in[1];
  const float* b1 = (const float*)d_in[2];
  const float* W2 = (const float*)d_in[3];
  const float* b2 = (const float*)d_in[4];
  float* out = (float*)d_out;

  char* ws = (char*)d_ws;
  half_t* Thi  = (half_t*)(ws);                                   // 2 MB
  half_t* Zth  = (half_t*)(ws + (size_t)2*1024*1024);             // 2 MB
  half_t* Pacc = (half_t*)(ws + (size_t)4*1024*1024);             // 16 MB
  float*  Pm   = (float*)(ws + (size_t)4*1024*1024 + (size_t)512*128*128*2);
  float*  Pl   = Pm + 512*128;

  hipLaunchKernelGGL(mlp_kernel,   dim3(128),  dim3(256), 0, stream, Z, W1, b1, W2, b2, Thi);
  hipLaunchKernelGGL(ztrans_kernel,dim3(512),  dim3(256), 0, stream, Z, Zth);
  hipLaunchKernelGGL(flash_kernel, dim3(512),  dim3(256), 0, stream, Thi, Zth, Pacc, Pm, Pl);
  hipLaunchKernelGGL(merge_kernel, dim3(1024), dim3(256), 0, stream, Z, Pacc, Pm, Pl, out);
}